// Round 1
// baseline (260.240 us; speedup 1.0000x reference)
//
#include <hip/hip_runtime.h>
#include <math.h>

#define NM 131072
#define PP 256
#define BB 32

#define CHUNKS 512
#define CHUNK_SZ 256   // NM / CHUNKS

#define INF_F 3.0e38f

// Branchless sorted insert into (d0<=d1<=d2) top-3 list.
__device__ __forceinline__ void ins3(float d, int i,
    float& d0, float& d1, float& d2, int& i0, int& i1, int& i2) {
  bool l0 = d < d0, l1 = d < d1, l2 = d < d2;
  d2 = l1 ? d1 : (l2 ? d : d2);
  i2 = l1 ? i1 : (l2 ? i : i2);
  d1 = l0 ? d0 : (l1 ? d : d1);
  i1 = l0 ? i0 : (l1 ? i : i1);
  d0 = l0 ? d : d0;
  i0 = l0 ? i : i0;
}

// Exact-fp32 distance matching the reference's (a-b)^2 + (c-d)^2 (no fma contraction).
__device__ __forceinline__ float dist2(float ax, float ay, float bx, float by) {
  float dx = ax - bx, dy = ay - by;
  return __fadd_rn(__fmul_rn(dx, dx), __fmul_rn(dy, dy));
}

// ---------- KNN A: for each pivotal point, top-3 nearest mesh points ----------
// Stage 1: block = mesh chunk (512 chunks x 256 points), thread = pivotal point.
// Mesh coords are wave-uniform per iteration -> scalar loads; pivotal in VGPRs.
__global__ void knnA_partial(const float* __restrict__ mesh, const float* __restrict__ piv,
                             float* __restrict__ candd, int* __restrict__ candi) {
  const int p = threadIdx.x;
  const int c = blockIdx.x;
  const float px = piv[2 * p], py = piv[2 * p + 1];
  float d0 = INF_F, d1 = INF_F, d2 = INF_F;
  int i0 = 0, i1 = 0, i2 = 0;
  const int base = c * CHUNK_SZ;
#pragma unroll 4
  for (int i = 0; i < CHUNK_SZ; ++i) {
    float mx = mesh[2 * (base + i)];
    float my = mesh[2 * (base + i) + 1];
    ins3(dist2(px, py, mx, my), base + i, d0, d1, d2, i0, i1, i2);
  }
  int o = (c * PP + p) * 3;
  candd[o] = d0; candd[o + 1] = d1; candd[o + 2] = d2;
  candi[o] = i0; candi[o + 1] = i1; candi[o + 2] = i2;
}

// Stage 2: block = pivotal point; tree-merge 512 candidate lists -> final top-3 + weights.
__global__ void knnA_merge(const float* __restrict__ candd, const int* __restrict__ candi,
                           float* __restrict__ wA, int* __restrict__ idxA) {
  const int p = blockIdx.x;
  const int t = threadIdx.x;
  __shared__ float sd[PP * 3];
  __shared__ int si[PP * 3];
  __shared__ float sd2[32 * 3];
  __shared__ int si2[32 * 3];

  float d0 = INF_F, d1 = INF_F, d2 = INF_F;
  int i0 = 0, i1 = 0, i2 = 0;
  for (int cc = 0; cc < 2; ++cc) {
    int o = ((2 * t + cc) * PP + p) * 3;
    for (int k = 0; k < 3; ++k) ins3(candd[o + k], candi[o + k], d0, d1, d2, i0, i1, i2);
  }
  sd[t * 3] = d0; sd[t * 3 + 1] = d1; sd[t * 3 + 2] = d2;
  si[t * 3] = i0; si[t * 3 + 1] = i1; si[t * 3 + 2] = i2;
  __syncthreads();
  if (t < 32) {
    d0 = d1 = d2 = INF_F; i0 = i1 = i2 = 0;
    for (int j = t * 8; j < t * 8 + 8; ++j)
      for (int k = 0; k < 3; ++k) ins3(sd[j * 3 + k], si[j * 3 + k], d0, d1, d2, i0, i1, i2);
    sd2[t * 3] = d0; sd2[t * 3 + 1] = d1; sd2[t * 3 + 2] = d2;
    si2[t * 3] = i0; si2[t * 3 + 1] = i1; si2[t * 3 + 2] = i2;
  }
  __syncthreads();
  if (t == 0) {
    d0 = d1 = d2 = INF_F; i0 = i1 = i2 = 0;
    for (int j = 0; j < 32; ++j)
      for (int k = 0; k < 3; ++k) ins3(sd2[j * 3 + k], si2[j * 3 + k], d0, d1, d2, i0, i1, i2);
    wA[p * 3 + 0] = 1.0f / fmaxf(d0, 1e-16f); idxA[p * 3 + 0] = i0;
    wA[p * 3 + 1] = 1.0f / fmaxf(d1, 1e-16f); idxA[p * 3 + 1] = i1;
    wA[p * 3 + 2] = 1.0f / fmaxf(d2, 1e-16f); idxA[p * 3 + 2] = i2;
  }
}

// ---------- Gather + LayerNorm + weighted interp -> y[B,256,3] ----------
// LayerNorm is applied ONLY at the 768 gathered rows per batch.
__global__ void gather_ln(const float* __restrict__ node, const float* __restrict__ wA,
                          const int* __restrict__ idxA, const float* __restrict__ gamma,
                          const float* __restrict__ beta, float* __restrict__ y) {
  const int b = blockIdx.x;
  const int p = threadIdx.x;
  const float g0 = gamma[0], g1 = gamma[1], g2 = gamma[2];
  const float be0 = beta[0], be1 = beta[1], be2 = beta[2];
  float num0 = 0.f, num1 = 0.f, num2 = 0.f, den = 0.f;
#pragma unroll
  for (int k = 0; k < 3; ++k) {
    int idx = idxA[p * 3 + k];
    float w = wA[p * 3 + k];
    const float* r = node + ((size_t)b * NM + idx) * 3;
    float a0 = r[0], a1 = r[1], a2 = r[2];
    float mu = (a0 + a1 + a2) * (1.0f / 3.0f);
    float e0 = a0 - mu, e1 = a1 - mu, e2 = a2 - mu;
    float var = (e0 * e0 + e1 * e1 + e2 * e2) * (1.0f / 3.0f);
    float sc = 1.0f / sqrtf(var + 1e-5f);
    float v0 = e0 * sc * g0 + be0, v1 = e1 * sc * g1 + be1, v2 = e2 * sc * g2 + be2;
    num0 += v0 * w; num1 += v1 * w; num2 += v2 * w; den += w;
  }
  int o = (b * PP + p) * 3;
  y[o] = num0 / den; y[o + 1] = num1 / den; y[o + 2] = num2 / den;
}

// ---------- q = y@Wf^T + bf + pos@Wp^T + bp ; Q = q@Wq^T+bq ; K = q@Wk^T+bk ----------
// Block = (b, tile of 8 p-rows), 128 threads: t<64 -> Q row e, t>=64 -> K row e.
__global__ void qqk_kernel(const float* __restrict__ y, const float* __restrict__ piv,
                           const float* __restrict__ Wf, const float* __restrict__ bf,
                           const float* __restrict__ Wp, const float* __restrict__ bp,
                           const float* __restrict__ ipw, const float* __restrict__ ipb,
                           float* __restrict__ Qm, float* __restrict__ Km) {
  const int b = blockIdx.x >> 5;
  const int ptile = (blockIdx.x & 31) * 8;
  const int t = threadIdx.x;
  const int e = t & 63;
  const int half = t >> 6;  // 0 -> Q, 1 -> K
  __shared__ float qs[8][64];

  {
    float wf0 = Wf[e * 3], wf1 = Wf[e * 3 + 1], wf2 = Wf[e * 3 + 2];
    float wp0 = Wp[e * 2], wp1 = Wp[e * 2 + 1];
    float cst = bf[e] + bp[e];
    for (int r = half; r < 8; r += 2) {
      int p = ptile + r;
      const float* yr = y + (b * PP + p) * 3;
      float pe = piv[2 * p] * wp0 + piv[2 * p + 1] * wp1;
      qs[r][e] = yr[0] * wf0 + yr[1] * wf1 + yr[2] * wf2 + cst + pe;
    }
  }
  __syncthreads();

  const int row = half * 64 + e;  // Wq rows 0..63, Wk rows 64..127 of in_proj_w
  float wreg[64];
  const float4* W4 = (const float4*)(ipw + row * 64);
#pragma unroll
  for (int j = 0; j < 16; ++j) {
    float4 v = W4[j];
    wreg[4 * j] = v.x; wreg[4 * j + 1] = v.y; wreg[4 * j + 2] = v.z; wreg[4 * j + 3] = v.w;
  }
  float bias = ipb[row];
  float* dst = half ? Km : Qm;
  for (int r = 0; r < 8; ++r) {
    float acc = bias;
#pragma unroll
    for (int j = 0; j < 64; ++j) acc += qs[r][j] * wreg[j];
    dst[(b * PP + ptile + r) * 64 + e] = acc;
  }
}

// ---------- attention: block = (b, q-row p); thread = key k ----------
__global__ void attn_kernel(const float* __restrict__ Qm, const float* __restrict__ Km,
                            const float* __restrict__ y, float* __restrict__ y2) {
  const int b = blockIdx.x >> 8;
  const int p = blockIdx.x & 255;
  const int t = threadIdx.x;
  const int lane = t & 63;
  const int wid = t >> 6;
  __shared__ float Qs[64];
  __shared__ float redm[4][4];
  __shared__ float reds[4][4];
  __shared__ float redy[4][3];

  if (t < 64) Qs[t] = Qm[(b * PP + p) * 64 + t];
  __syncthreads();

  const float4* K4 = (const float4*)(Km + (b * PP + t) * 64);
  float s[4] = {0.f, 0.f, 0.f, 0.f};
#pragma unroll
  for (int j = 0; j < 16; ++j) {
    float4 kv = K4[j];
    int h = j >> 2;
    s[h] += Qs[4 * j] * kv.x + Qs[4 * j + 1] * kv.y + Qs[4 * j + 2] * kv.z + Qs[4 * j + 3] * kv.w;
  }
  float m[4];
#pragma unroll
  for (int h = 0; h < 4; ++h) { s[h] *= 0.25f; m[h] = s[h]; }
#pragma unroll
  for (int off = 32; off >= 1; off >>= 1)
#pragma unroll
    for (int h = 0; h < 4; ++h) m[h] = fmaxf(m[h], __shfl_xor(m[h], off, 64));
  if (lane == 0) { redm[wid][0] = m[0]; redm[wid][1] = m[1]; redm[wid][2] = m[2]; redm[wid][3] = m[3]; }
  __syncthreads();
  float ev[4], sm[4];
#pragma unroll
  for (int h = 0; h < 4; ++h) {
    float mx = fmaxf(fmaxf(redm[0][h], redm[1][h]), fmaxf(redm[2][h], redm[3][h]));
    ev[h] = expf(s[h] - mx);
    sm[h] = ev[h];
  }
#pragma unroll
  for (int off = 32; off >= 1; off >>= 1)
#pragma unroll
    for (int h = 0; h < 4; ++h) sm[h] += __shfl_xor(sm[h], off, 64);
  if (lane == 0) { reds[wid][0] = sm[0]; reds[wid][1] = sm[1]; reds[wid][2] = sm[2]; reds[wid][3] = sm[3]; }
  __syncthreads();
  float aw = 0.f;
#pragma unroll
  for (int h = 0; h < 4; ++h) {
    float tot = reds[0][h] + reds[1][h] + reds[2][h] + reds[3][h];
    aw += ev[h] / tot;
  }
  aw *= 0.25f;

  const float* yr = y + (b * PP + t) * 3;
  float a0 = aw * yr[0], a1 = aw * yr[1], a2 = aw * yr[2];
#pragma unroll
  for (int off = 32; off >= 1; off >>= 1) {
    a0 += __shfl_xor(a0, off, 64);
    a1 += __shfl_xor(a1, off, 64);
    a2 += __shfl_xor(a2, off, 64);
  }
  if (lane == 0) { redy[wid][0] = a0; redy[wid][1] = a1; redy[wid][2] = a2; }
  __syncthreads();
  if (t == 0) {
    float* o = y2 + (b * PP + p) * 3;
    o[0] = redy[0][0] + redy[1][0] + redy[2][0] + redy[3][0];
    o[1] = redy[0][1] + redy[1][1] + redy[2][1] + redy[3][1];
    o[2] = redy[0][2] + redy[1][2] + redy[2][2] + redy[3][2];
  }
}

// ---------- KNN B + output: thread = mesh point; KNN once, reused for all 32 batches ----------
__global__ void knnB_out(const float* __restrict__ mesh, const float* __restrict__ piv,
                         const float* __restrict__ y2, float* __restrict__ out) {
  const int m = blockIdx.x * blockDim.x + threadIdx.x;
  const float mx = mesh[2 * m], my = mesh[2 * m + 1];
  float d0 = INF_F, d1 = INF_F, d2 = INF_F;
  int i0 = 0, i1 = 0, i2 = 0;
#pragma unroll 4
  for (int i = 0; i < PP; ++i) {
    float px = piv[2 * i], py = piv[2 * i + 1];  // wave-uniform -> scalar loads
    ins3(dist2(mx, my, px, py), i, d0, d1, d2, i0, i1, i2);
  }
  float w0 = 1.0f / fmaxf(d0, 1e-16f);
  float w1 = 1.0f / fmaxf(d1, 1e-16f);
  float w2 = 1.0f / fmaxf(d2, 1e-16f);
  float inv = 1.0f / (w0 + w1 + w2);
  int o0 = i0 * 3, o1 = i1 * 3, o2 = i2 * 3;
  for (int b = 0; b < BB; ++b) {
    const float* yb = y2 + b * PP * 3;
    float n0 = w0 * yb[o0] + w1 * yb[o1] + w2 * yb[o2];
    float n1 = w0 * yb[o0 + 1] + w1 * yb[o1 + 1] + w2 * yb[o2 + 1];
    float n2 = w0 * yb[o0 + 2] + w1 * yb[o1 + 2] + w2 * yb[o2 + 2];
    float* op = out + ((size_t)b * NM + m) * 3;
    op[0] = n0 * inv; op[1] = n1 * inv; op[2] = n2 * inv;
  }
}

extern "C" void kernel_launch(void* const* d_in, const int* in_sizes, int n_in,
                              void* d_out, int out_size, void* d_ws, size_t ws_size,
                              hipStream_t stream) {
  const float* node  = (const float*)d_in[0];
  const float* mesh  = (const float*)d_in[1];
  const float* piv   = (const float*)d_in[2];
  const float* gamma = (const float*)d_in[3];
  const float* beta  = (const float*)d_in[4];
  const float* Wf    = (const float*)d_in[5];
  const float* bf    = (const float*)d_in[6];
  const float* Wp    = (const float*)d_in[7];
  const float* bp    = (const float*)d_in[8];
  const float* ipw   = (const float*)d_in[9];
  const float* ipb   = (const float*)d_in[10];
  float* out = (float*)d_out;

  // workspace layout (floats), total ~7.5 MB
  float* candd = (float*)d_ws;                     // CHUNKS*PP*3
  int*   candi = (int*)(candd + CHUNKS * PP * 3);  // CHUNKS*PP*3
  float* wA    = (float*)(candi + CHUNKS * PP * 3);// PP*3
  int*   idxA  = (int*)(wA + PP * 3);              // PP*3
  float* y     = (float*)(idxA + PP * 3);          // BB*PP*3
  float* Qm    = y + BB * PP * 3;                  // BB*PP*64
  float* Km    = Qm + BB * PP * 64;                // BB*PP*64
  float* y2    = Km + BB * PP * 64;                // BB*PP*3

  knnA_partial<<<CHUNKS, PP, 0, stream>>>(mesh, piv, candd, candi);
  knnA_merge<<<PP, 256, 0, stream>>>(candd, candi, wA, idxA);
  gather_ln<<<BB, PP, 0, stream>>>(node, wA, idxA, gamma, beta, y);
  qqk_kernel<<<BB * 32, 128, 0, stream>>>(y, piv, Wf, bf, Wp, bp, ipw, ipb, Qm, Km);
  attn_kernel<<<BB * PP, 256, 0, stream>>>(Qm, Km, y, y2);
  knnB_out<<<NM / 256, 256, 0, stream>>>(mesh, piv, y2, out);
}

// Round 2
// 223.998 us; speedup vs baseline: 1.1618x; 1.1618x over previous
//
#include <hip/hip_runtime.h>
#include <math.h>

#define NM 131072
#define PP 256
#define BB 32

#define CHUNKS 512
#define CHUNK_SZ 256   // NM / CHUNKS

#define INF_F 3.0e38f

// Branchless sorted insert into (d0<=d1<=d2) top-3 list.
__device__ __forceinline__ void ins3(float d, int i,
    float& d0, float& d1, float& d2, int& i0, int& i1, int& i2) {
  bool l0 = d < d0, l1 = d < d1, l2 = d < d2;
  d2 = l1 ? d1 : (l2 ? d : d2);
  i2 = l1 ? i1 : (l2 ? i : i2);
  d1 = l0 ? d0 : (l1 ? d : d1);
  i1 = l0 ? i0 : (l1 ? i : i1);
  d0 = l0 ? d : d0;
  i0 = l0 ? i : i0;
}

// Exact-fp32 distance matching the reference's (a-b)^2 + (c-d)^2 (no fma contraction).
__device__ __forceinline__ float dist2(float ax, float ay, float bx, float by) {
  float dx = ax - bx, dy = ay - by;
  return __fadd_rn(__fmul_rn(dx, dx), __fmul_rn(dy, dy));
}

// ---------- KNN A: for each pivotal point, top-3 nearest mesh points ----------
__global__ void knnA_partial(const float* __restrict__ mesh, const float* __restrict__ piv,
                             float* __restrict__ candd, int* __restrict__ candi) {
  const int p = threadIdx.x;
  const int c = blockIdx.x;
  const float px = piv[2 * p], py = piv[2 * p + 1];
  float d0 = INF_F, d1 = INF_F, d2 = INF_F;
  int i0 = 0, i1 = 0, i2 = 0;
  const int base = c * CHUNK_SZ;
#pragma unroll 4
  for (int i = 0; i < CHUNK_SZ; ++i) {
    float mx = mesh[2 * (base + i)];
    float my = mesh[2 * (base + i) + 1];
    ins3(dist2(px, py, mx, my), base + i, d0, d1, d2, i0, i1, i2);
  }
  int o = (c * PP + p) * 3;
  candd[o] = d0; candd[o + 1] = d1; candd[o + 2] = d2;
  candi[o] = i0; candi[o + 1] = i1; candi[o + 2] = i2;
}

__global__ void knnA_merge(const float* __restrict__ candd, const int* __restrict__ candi,
                           float* __restrict__ wA, int* __restrict__ idxA) {
  const int p = blockIdx.x;
  const int t = threadIdx.x;
  __shared__ float sd[PP * 3];
  __shared__ int si[PP * 3];
  __shared__ float sd2[32 * 3];
  __shared__ int si2[32 * 3];

  float d0 = INF_F, d1 = INF_F, d2 = INF_F;
  int i0 = 0, i1 = 0, i2 = 0;
  for (int cc = 0; cc < 2; ++cc) {
    int o = ((2 * t + cc) * PP + p) * 3;
    for (int k = 0; k < 3; ++k) ins3(candd[o + k], candi[o + k], d0, d1, d2, i0, i1, i2);
  }
  sd[t * 3] = d0; sd[t * 3 + 1] = d1; sd[t * 3 + 2] = d2;
  si[t * 3] = i0; si[t * 3 + 1] = i1; si[t * 3 + 2] = i2;
  __syncthreads();
  if (t < 32) {
    d0 = d1 = d2 = INF_F; i0 = i1 = i2 = 0;
    for (int j = t * 8; j < t * 8 + 8; ++j)
      for (int k = 0; k < 3; ++k) ins3(sd[j * 3 + k], si[j * 3 + k], d0, d1, d2, i0, i1, i2);
    sd2[t * 3] = d0; sd2[t * 3 + 1] = d1; sd2[t * 3 + 2] = d2;
    si2[t * 3] = i0; si2[t * 3 + 1] = i1; si2[t * 3 + 2] = i2;
  }
  __syncthreads();
  if (t == 0) {
    d0 = d1 = d2 = INF_F; i0 = i1 = i2 = 0;
    for (int j = 0; j < 32; ++j)
      for (int k = 0; k < 3; ++k) ins3(sd2[j * 3 + k], si2[j * 3 + k], d0, d1, d2, i0, i1, i2);
    wA[p * 3 + 0] = 1.0f / fmaxf(d0, 1e-16f); idxA[p * 3 + 0] = i0;
    wA[p * 3 + 1] = 1.0f / fmaxf(d1, 1e-16f); idxA[p * 3 + 1] = i1;
    wA[p * 3 + 2] = 1.0f / fmaxf(d2, 1e-16f); idxA[p * 3 + 2] = i2;
  }
}

// ---------- Gather + LayerNorm + weighted interp -> y[B,256,3] ----------
// 128 blocks x 64 threads: spread the scattered HBM reads across more CUs.
__global__ void gather_ln(const float* __restrict__ node, const float* __restrict__ wA,
                          const int* __restrict__ idxA, const float* __restrict__ gamma,
                          const float* __restrict__ beta, float* __restrict__ y) {
  const int b = blockIdx.x >> 2;
  const int p = ((blockIdx.x & 3) << 6) + threadIdx.x;
  const float g0 = gamma[0], g1 = gamma[1], g2 = gamma[2];
  const float be0 = beta[0], be1 = beta[1], be2 = beta[2];
  float num0 = 0.f, num1 = 0.f, num2 = 0.f, den = 0.f;
#pragma unroll
  for (int k = 0; k < 3; ++k) {
    int idx = idxA[p * 3 + k];
    float w = wA[p * 3 + k];
    const float* r = node + ((size_t)b * NM + idx) * 3;
    float a0 = r[0], a1 = r[1], a2 = r[2];
    float mu = (a0 + a1 + a2) * (1.0f / 3.0f);
    float e0 = a0 - mu, e1 = a1 - mu, e2 = a2 - mu;
    float var = (e0 * e0 + e1 * e1 + e2 * e2) * (1.0f / 3.0f);
    float sc = 1.0f / sqrtf(var + 1e-5f);
    float v0 = e0 * sc * g0 + be0, v1 = e1 * sc * g1 + be1, v2 = e2 * sc * g2 + be2;
    num0 += v0 * w; num1 += v1 * w; num2 += v2 * w; den += w;
  }
  int o = (b * PP + p) * 3;
  y[o] = num0 / den; y[o + 1] = num1 / den; y[o + 2] = num2 / den;
}

// ---------- q/Q/K projection; output head-major Qh/Kh [b][h][q][16] ----------
__global__ void qqk_kernel(const float* __restrict__ y, const float* __restrict__ piv,
                           const float* __restrict__ Wf, const float* __restrict__ bf,
                           const float* __restrict__ Wp, const float* __restrict__ bp,
                           const float* __restrict__ ipw, const float* __restrict__ ipb,
                           float* __restrict__ Qh, float* __restrict__ Kh) {
  const int b = blockIdx.x >> 5;
  const int ptile = (blockIdx.x & 31) * 8;
  const int t = threadIdx.x;
  const int e = t & 63;
  const int half = t >> 6;  // 0 -> Q, 1 -> K
  __shared__ float qs[8][64];

  {
    float wf0 = Wf[e * 3], wf1 = Wf[e * 3 + 1], wf2 = Wf[e * 3 + 2];
    float wp0 = Wp[e * 2], wp1 = Wp[e * 2 + 1];
    float cst = bf[e] + bp[e];
    for (int r = half; r < 8; r += 2) {
      int p = ptile + r;
      const float* yr = y + (b * PP + p) * 3;
      float pe = piv[2 * p] * wp0 + piv[2 * p + 1] * wp1;
      qs[r][e] = yr[0] * wf0 + yr[1] * wf1 + yr[2] * wf2 + cst + pe;
    }
  }
  __syncthreads();

  const int row = half * 64 + e;
  float wreg[64];
  const float4* W4 = (const float4*)(ipw + row * 64);
#pragma unroll
  for (int j = 0; j < 16; ++j) {
    float4 v = W4[j];
    wreg[4 * j] = v.x; wreg[4 * j + 1] = v.y; wreg[4 * j + 2] = v.z; wreg[4 * j + 3] = v.w;
  }
  float bias = ipb[row];
  float* dst = half ? Kh : Qh;
  const int h = e >> 4, d = e & 15;
  for (int r = 0; r < 8; ++r) {
    float acc = bias;
#pragma unroll
    for (int j = 0; j < 64; ++j) acc += qs[r][j] * wreg[j];
    int p = ptile + r;
    dst[(((b * 4 + h) * PP) + p) * 16 + d] = acc;
  }
}

// ---------- attention: block = (b, h, q-half); thread = q-row; online softmax ----------
__global__ void attn_kernel(const float* __restrict__ Qh, const float* __restrict__ Kh,
                            const float* __restrict__ y, float* __restrict__ y2) {
  const int b = blockIdx.x >> 3;
  const int h = (blockIdx.x >> 1) & 3;
  const int qh = blockIdx.x & 1;
  const int t = threadIdx.x;          // 128 threads
  const int q = qh * 128 + t;

  __shared__ float Ks[PP * 16];       // 16 KB, head h's K
  __shared__ float ys[PP * 3];        // 3 KB

  // coalesced stage of K_h and y
  {
    const float4* src = (const float4*)(Kh + (size_t)(b * 4 + h) * PP * 16);
    float4* dst = (float4*)Ks;
#pragma unroll
    for (int j = 0; j < 8; ++j) dst[j * 128 + t] = src[j * 128 + t];
    const float* ysrc = y + b * PP * 3;
#pragma unroll
    for (int j = 0; j < 6; ++j) ys[j * 128 + t] = ysrc[j * 128 + t];
  }
  __syncthreads();

  const float4* q4 = (const float4*)(Qh + ((size_t)((b * 4 + h) * PP) + q) * 16);
  float4 qa = q4[0], qb = q4[1], qc = q4[2], qd = q4[3];

  float m = -INF_F, l = 0.f, a0 = 0.f, a1 = 0.f, a2 = 0.f;
#pragma unroll 4
  for (int k = 0; k < PP; ++k) {
    const float4* kr = (const float4*)(Ks + k * 16);   // broadcast read
    float4 k0 = kr[0], k1 = kr[1], k2 = kr[2], k3 = kr[3];
    float dot = qa.x * k0.x + qa.y * k0.y + qa.z * k0.z + qa.w * k0.w
              + qb.x * k1.x + qb.y * k1.y + qb.z * k1.z + qb.w * k1.w
              + qc.x * k2.x + qc.y * k2.y + qc.z * k2.z + qc.w * k2.w
              + qd.x * k3.x + qd.y * k3.y + qd.z * k3.z + qd.w * k3.w;
    float s = dot * 0.25f;            // 1/sqrt(DH=16)
    float mn = fmaxf(m, s);
    float p = __expf(s - mn);
    float sc = __expf(m - mn);
    float y0 = ys[k * 3], y1 = ys[k * 3 + 1], yy2 = ys[k * 3 + 2];
    l = l * sc + p;
    a0 = a0 * sc + p * y0;
    a1 = a1 * sc + p * y1;
    a2 = a2 * sc + p * yy2;
    m = mn;
  }
  float inv = 0.25f / l;              // mean over 4 heads
  float* o = y2 + (b * PP + q) * 3;
  atomicAdd(o + 0, a0 * inv);
  atomicAdd(o + 1, a1 * inv);
  atomicAdd(o + 2, a2 * inv);
}

// ---------- KNN B + output ----------
__global__ void knnB_out(const float* __restrict__ mesh, const float* __restrict__ piv,
                         const float* __restrict__ y2, float* __restrict__ out) {
  const int m = blockIdx.x * blockDim.x + threadIdx.x;
  const float mx = mesh[2 * m], my = mesh[2 * m + 1];
  float d0 = INF_F, d1 = INF_F, d2 = INF_F;
  int i0 = 0, i1 = 0, i2 = 0;
#pragma unroll 4
  for (int i = 0; i < PP; ++i) {
    float px = piv[2 * i], py = piv[2 * i + 1];  // wave-uniform -> scalar loads
    ins3(dist2(mx, my, px, py), i, d0, d1, d2, i0, i1, i2);
  }
  float w0 = 1.0f / fmaxf(d0, 1e-16f);
  float w1 = 1.0f / fmaxf(d1, 1e-16f);
  float w2 = 1.0f / fmaxf(d2, 1e-16f);
  float inv = 1.0f / (w0 + w1 + w2);
  int o0 = i0 * 3, o1 = i1 * 3, o2 = i2 * 3;
  for (int b = 0; b < BB; ++b) {
    const float* yb = y2 + b * PP * 3;
    float n0 = w0 * yb[o0] + w1 * yb[o1] + w2 * yb[o2];
    float n1 = w0 * yb[o0 + 1] + w1 * yb[o1 + 1] + w2 * yb[o2 + 1];
    float n2 = w0 * yb[o0 + 2] + w1 * yb[o1 + 2] + w2 * yb[o2 + 2];
    float* op = out + ((size_t)b * NM + m) * 3;
    op[0] = n0 * inv; op[1] = n1 * inv; op[2] = n2 * inv;
  }
}

extern "C" void kernel_launch(void* const* d_in, const int* in_sizes, int n_in,
                              void* d_out, int out_size, void* d_ws, size_t ws_size,
                              hipStream_t stream) {
  const float* node  = (const float*)d_in[0];
  const float* mesh  = (const float*)d_in[1];
  const float* piv   = (const float*)d_in[2];
  const float* gamma = (const float*)d_in[3];
  const float* beta  = (const float*)d_in[4];
  const float* Wf    = (const float*)d_in[5];
  const float* bf    = (const float*)d_in[6];
  const float* Wp    = (const float*)d_in[7];
  const float* bp    = (const float*)d_in[8];
  const float* ipw   = (const float*)d_in[9];
  const float* ipb   = (const float*)d_in[10];
  float* out = (float*)d_out;

  // workspace layout (floats)
  float* candd = (float*)d_ws;                     // CHUNKS*PP*3
  int*   candi = (int*)(candd + CHUNKS * PP * 3);  // CHUNKS*PP*3
  float* wA    = (float*)(candi + CHUNKS * PP * 3);// PP*3
  int*   idxA  = (int*)(wA + PP * 3);              // PP*3
  float* y     = (float*)(idxA + PP * 3);          // BB*PP*3
  float* Qh    = y + BB * PP * 3;                  // BB*4*PP*16
  float* Kh    = Qh + BB * PP * 64;                // BB*4*PP*16
  float* y2    = Kh + BB * PP * 64;                // BB*PP*3

  hipMemsetAsync(y2, 0, BB * PP * 3 * sizeof(float), stream);

  knnA_partial<<<CHUNKS, PP, 0, stream>>>(mesh, piv, candd, candi);
  knnA_merge<<<PP, 256, 0, stream>>>(candd, candi, wA, idxA);
  gather_ln<<<BB * 4, 64, 0, stream>>>(node, wA, idxA, gamma, beta, y);
  qqk_kernel<<<BB * 32, 128, 0, stream>>>(y, piv, Wf, bf, Wp, bp, ipw, ipb, Qh, Kh);
  attn_kernel<<<BB * 4 * 2, 128, 0, stream>>>(Qh, Kh, y, y2);
  knnB_out<<<NM / 256, 256, 0, stream>>>(mesh, piv, y2, out);
}